// Round 1
// baseline (751.694 us; speedup 1.0000x reference)
//
#include <hip/hip_runtime.h>
#include <hip/hip_bf16.h>

namespace {
constexpr int kB  = 8;
constexpr int kC  = 256;
constexpr int kN  = 1024;
constexpr int kV  = 12;
constexpr int kNV = kN * kV;          // 12288
constexpr int kP  = kB * kNV;         // 98304 positions
constexpr int kD  = 64;
constexpr float kEps = 1e-5f;

// workspace layout, in floats
constexpr size_t OFF_PARAMS = 0;                        // 4 stages * (a[256], b[256]) = 2048
constexpr size_t OFF_SUMS   = 2048;                     // 4 stages * (sum[256], sq[256]) = 2048
constexpr size_t OFF_Y1     = 4096;                     // [64][P]
constexpr size_t OFF_Y3     = OFF_Y1 + (size_t)kD * kP; // [256][P]
constexpr size_t OFF_Y24    = OFF_Y3 + (size_t)kC * kP; // [256][P] (y2, later reused for y4)
} // namespace

// GEMM: out[M,P] = mask .* (W[M,K] @ act(in)[K,P] + bias)
// MODE 0: input is voints_feats layout [B,C,N,V], read raw (stage 1)
// MODE 1: input is y_prev [K,P], apply act(y) = mask .* relu(a*y + b)
// MODE 2: MODE 1 + add raw X0 (voints layout) -> x1 = x + act3(y3) (stage 4)
template<int M, int K, int MODE>
__global__ __launch_bounds__(256) void gemm_bn_kernel(
    const float* __restrict__ W, const float* __restrict__ bias,
    const float* __restrict__ Y, const float* __restrict__ X0,
    const float* __restrict__ mask,
    const float* __restrict__ actA, const float* __restrict__ actB,
    float* __restrict__ out)
{
    __shared__ float Ws[16][64];   // [k][m]
    __shared__ float Xs[16][64];   // [k][p]

    const int tid = threadIdx.x;
    const int tx = tid & 15, ty = tid >> 4;
    const int colBase = blockIdx.x * 64;        // global position tile (never crosses b: 12288 % 64 == 0)
    const int m0 = blockIdx.y * 64;
    const int b  = colBase / kNV;
    const int q  = colBase - b * kNV;

    const int wm = tid >> 2;          // 0..63 row within W tile
    const int wk = (tid & 3) << 2;    // 0,4,8,12
    const int xk = tid >> 4;          // 0..15 k within tile
    const int xp = (tid & 15) << 2;   // 0..60 col within tile

    float acc[4][4] = {};

    for (int k0 = 0; k0 < K; k0 += 16) {
        const float4 w4 = *(const float4*)&W[(size_t)(m0 + wm) * K + k0 + wk];
        const int krow = k0 + xk;
        float4 v4;
        if constexpr (MODE == 0) {
            v4 = *(const float4*)&Y[(size_t)(b * kC + krow) * kNV + q + xp];
        } else {
            v4 = *(const float4*)&Y[(size_t)krow * kP + colBase + xp];
            const float a  = actA[krow];
            const float bb = actB[krow];
            const float4 mm = *(const float4*)&mask[colBase + xp];
            v4.x = mm.x * fmaxf(fmaf(a, v4.x, bb), 0.f);
            v4.y = mm.y * fmaxf(fmaf(a, v4.y, bb), 0.f);
            v4.z = mm.z * fmaxf(fmaf(a, v4.z, bb), 0.f);
            v4.w = mm.w * fmaxf(fmaf(a, v4.w, bb), 0.f);
            if constexpr (MODE == 2) {
                const float4 x4 = *(const float4*)&X0[(size_t)(b * kC + krow) * kNV + q + xp];
                v4.x += x4.x; v4.y += x4.y; v4.z += x4.z; v4.w += x4.w;
            }
        }
        __syncthreads();
        Ws[wk + 0][wm] = w4.x;
        Ws[wk + 1][wm] = w4.y;
        Ws[wk + 2][wm] = w4.z;
        Ws[wk + 3][wm] = w4.w;
        *(float4*)&Xs[xk][xp] = v4;
        __syncthreads();
        #pragma unroll
        for (int kk = 0; kk < 16; ++kk) {
            float wv[4], xv[4];
            *(float4*)wv = *(const float4*)&Ws[kk][ty << 2];
            *(float4*)xv = *(const float4*)&Xs[kk][tx << 2];
            #pragma unroll
            for (int i = 0; i < 4; ++i)
                #pragma unroll
                for (int j = 0; j < 4; ++j)
                    acc[i][j] = fmaf(wv[i], xv[j], acc[i][j]);
        }
    }

    const float4 mm = *(const float4*)&mask[colBase + (tx << 2)];
    #pragma unroll
    for (int i = 0; i < 4; ++i) {
        const int r = m0 + (ty << 2) + i;
        const float bi = bias[r];
        float4 o;
        o.x = mm.x * (acc[i][0] + bi);
        o.y = mm.y * (acc[i][1] + bi);
        o.z = mm.z * (acc[i][2] + bi);
        o.w = mm.w * (acc[i][3] + bi);
        *(float4*)&out[(size_t)r * kP + colBase + (tx << 2)] = o;
    }
}

// per-channel sum / sumsq over P elements (BN counts masked zeros too: divisor = P)
__global__ __launch_bounds__(256) void stats_kernel(
    const float* __restrict__ y, float* __restrict__ sum, float* __restrict__ sumsq)
{
    const int m = blockIdx.x;
    const float* row = y + (size_t)m * kP;
    const int base = blockIdx.y * (kP / 12);   // 8192-wide chunk
    float s = 0.f, s2 = 0.f;
    for (int i = threadIdx.x * 4; i < kP / 12; i += 256 * 4) {
        const float4 v = *(const float4*)&row[base + i];
        s  += v.x + v.y + v.z + v.w;
        s2 += v.x * v.x + v.y * v.y + v.z * v.z + v.w * v.w;
    }
    #pragma unroll
    for (int off = 32; off > 0; off >>= 1) {
        s  += __shfl_down(s, off, 64);
        s2 += __shfl_down(s2, off, 64);
    }
    __shared__ float ls[8];
    const int wid = threadIdx.x >> 6;
    if ((threadIdx.x & 63) == 0) { ls[wid] = s; ls[4 + wid] = s2; }
    __syncthreads();
    if (threadIdx.x == 0) {
        atomicAdd(&sum[m],   ls[0] + ls[1] + ls[2] + ls[3]);
        atomicAdd(&sumsq[m], ls[4] + ls[5] + ls[6] + ls[7]);
    }
}

// fold BN into per-channel affine: act(y) = relu(a*y + b) [* mask applied by consumer]
__global__ void finalize_kernel(
    const float* __restrict__ sum, const float* __restrict__ sumsq,
    const float* __restrict__ g, const float* __restrict__ bt,
    float* __restrict__ a, float* __restrict__ bcoef, int M)
{
    const int m = threadIdx.x;
    if (m < M) {
        const float mu  = sum[m] * (1.f / kP);
        const float var = sumsq[m] * (1.f / kP) - mu * mu;
        const float inv = rsqrtf(var + kEps);
        const float A = inv * g[m];
        a[m] = A;
        bcoef[m] = fmaf(-mu, A, bt[m]);
    }
}

// out = x + act3(y3) + act4(y4)
__global__ __launch_bounds__(256) void final_kernel(
    const float* __restrict__ x, const float* __restrict__ y3, const float* __restrict__ y4,
    const float* __restrict__ mask,
    const float* __restrict__ a3, const float* __restrict__ b3,
    const float* __restrict__ a4, const float* __restrict__ b4,
    float* __restrict__ out)
{
    const size_t flat = ((size_t)blockIdx.x * 256 + threadIdx.x) * 4;
    const int bc = (int)(flat / kNV);            // b*C + c
    const int q  = (int)(flat - (size_t)bc * kNV);
    const int b  = bc >> 8;                      // / 256
    const int c  = bc & 255;
    const int p  = b * kNV + q;
    const float4 xv = *(const float4*)&x[flat];
    const float4 m  = *(const float4*)&mask[p];
    const float4 v3 = *(const float4*)&y3[(size_t)c * kP + p];
    const float4 v4 = *(const float4*)&y4[(size_t)c * kP + p];
    const float A3 = a3[c], B3 = b3[c], A4 = a4[c], B4 = b4[c];
    float4 o;
    o.x = xv.x + m.x * (fmaxf(fmaf(A3, v3.x, B3), 0.f) + fmaxf(fmaf(A4, v4.x, B4), 0.f));
    o.y = xv.y + m.y * (fmaxf(fmaf(A3, v3.y, B3), 0.f) + fmaxf(fmaf(A4, v4.y, B4), 0.f));
    o.z = xv.z + m.z * (fmaxf(fmaf(A3, v3.z, B3), 0.f) + fmaxf(fmaf(A4, v4.z, B4), 0.f));
    o.w = xv.w + m.w * (fmaxf(fmaf(A3, v3.w, B3), 0.f) + fmaxf(fmaf(A4, v4.w, B4), 0.f));
    *(float4*)&out[flat] = o;
}

extern "C" void kernel_launch(void* const* d_in, const int* in_sizes, int n_in,
                              void* d_out, int out_size, void* d_ws, size_t ws_size,
                              hipStream_t stream)
{
    const float* x    = (const float*)d_in[0];
    const float* mask = (const float*)d_in[1];
    const float* We   = (const float*)d_in[2];
    const float* be   = (const float*)d_in[3];
    const float* ge   = (const float*)d_in[4];
    const float* bne  = (const float*)d_in[5];
    const float* Wa   = (const float*)d_in[6];
    const float* ba   = (const float*)d_in[7];
    const float* ga   = (const float*)d_in[8];
    const float* bna  = (const float*)d_in[9];
    const float* Wo   = (const float*)d_in[10];
    const float* bo   = (const float*)d_in[11];
    const float* go   = (const float*)d_in[12];
    const float* bno  = (const float*)d_in[13];
    const float* Wf   = (const float*)d_in[14];
    const float* bf   = (const float*)d_in[15];
    const float* gf   = (const float*)d_in[16];
    const float* bnf  = (const float*)d_in[17];
    float* out = (float*)d_out;
    float* ws  = (float*)d_ws;

    float* params = ws + OFF_PARAMS;
    float* sums   = ws + OFF_SUMS;
    float* y1     = ws + OFF_Y1;
    float* y3     = ws + OFF_Y3;
    float* y24    = ws + OFF_Y24;   // holds y2, then reused for y4

    hipMemsetAsync(sums, 0, 2048 * sizeof(float), stream);

    const dim3 blk(256);
    const dim3 gTiles1(kP / 64, 1);
    const dim3 gTiles4(kP / 64, 4);

    // stage 1: y1 = mask .* (We @ x + be)   [64 x P]
    gemm_bn_kernel<64, 256, 0><<<gTiles1, blk, 0, stream>>>(
        We, be, x, nullptr, mask, nullptr, nullptr, y1);
    stats_kernel<<<dim3(64, 12), blk, 0, stream>>>(y1, sums + 0, sums + 256);
    finalize_kernel<<<1, 64, 0, stream>>>(sums + 0, sums + 256, ge, bne,
                                          params + 0, params + 256, 64);

    // stage 2: y2 = mask .* (Wa_v @ act1(y1) + ba_v)   [256 x P]
    // only the v-chunk (rows 512:768) of Wa matters: softmax row-sums are 1,
    // so attention output == v exactly.
    gemm_bn_kernel<256, 64, 1><<<gTiles4, blk, 0, stream>>>(
        Wa + 512 * kD, ba + 512, y1, nullptr, mask, params + 0, params + 256, y24);
    stats_kernel<<<dim3(256, 12), blk, 0, stream>>>(y24, sums + 512, sums + 768);
    finalize_kernel<<<1, 256, 0, stream>>>(sums + 512, sums + 768, ga + 512, bna + 512,
                                           params + 512, params + 768, 256);

    // stage 3: y3 = mask .* (Wo @ act2(y2) + bo)   [256 x P]
    gemm_bn_kernel<256, 256, 1><<<gTiles4, blk, 0, stream>>>(
        Wo, bo, y24, nullptr, mask, params + 512, params + 768, y3);
    stats_kernel<<<dim3(256, 12), blk, 0, stream>>>(y3, sums + 1024, sums + 1280);
    finalize_kernel<<<1, 256, 0, stream>>>(sums + 1024, sums + 1280, go, bno,
                                           params + 1024, params + 1280, 256);

    // stage 4: y4 = mask .* (Wf @ (x + act3(y3)) + bf)   [256 x P] (into y2's buffer)
    gemm_bn_kernel<256, 256, 2><<<gTiles4, blk, 0, stream>>>(
        Wf, bf, y3, x, mask, params + 1024, params + 1280, y24);
    stats_kernel<<<dim3(256, 12), blk, 0, stream>>>(y24, sums + 1536, sums + 1792);
    finalize_kernel<<<1, 256, 0, stream>>>(sums + 1536, sums + 1792, gf, bnf,
                                           params + 1536, params + 1792, 256);

    // final: out = x + act3(y3) + act4(y4)
    final_kernel<<<(kC * kP / 4) / 256, blk, 0, stream>>>(
        x, y3, y24, mask, params + 1024, params + 1280, params + 1536, params + 1792, out);
}

// Round 2
// 432.070 us; speedup vs baseline: 1.7398x; 1.7398x over previous
//
#include <hip/hip_runtime.h>
#include <hip/hip_bf16.h>

typedef __attribute__((ext_vector_type(8))) __bf16 bf16x8;
typedef __attribute__((ext_vector_type(4))) float floatx4;
typedef __attribute__((ext_vector_type(8))) unsigned short ushort8;

namespace {
constexpr int kC  = 256;
constexpr int kNV = 1024 * 12;        // 12288
constexpr int kP  = 8 * kNV;          // 98304 positions
constexpr float kEps = 1e-5f;

// ws layout in float units
constexpr size_t OFF_PARAMS = 0;                         // 4 stages x [a(256)|b(256)]
constexpr size_t OFF_PART   = 2048;                      // 4 stages x 8 buckets x 512
constexpr size_t OFF_WB     = 2048 + 16384;              // 163840 ushort = 81920 floats
constexpr size_t OFF_Y1     = OFF_WB + 81920;            // 98304x64 bf16
constexpr size_t OFF_Y2     = OFF_Y1 + (size_t)kP * 64 / 2;   // 98304x256 bf16 (also y4)
constexpr size_t OFF_Y3     = OFF_Y2 + (size_t)kP * 256 / 2;
} // namespace

__device__ __forceinline__ unsigned short f2bf(float f) {
    unsigned int u = __builtin_bit_cast(unsigned int, f);
    u += 0x7FFFu + ((u >> 16) & 1u);
    return (unsigned short)(u >> 16);
}
__device__ __forceinline__ float bf2f(unsigned short h) {
    unsigned int u = ((unsigned int)h) << 16;
    return __builtin_bit_cast(float, u);
}

// convert the 4 weight matrices (We, Wa_v slice, Wo, Wf) to bf16, packed contiguously
__global__ void convw_kernel(const float* __restrict__ We, const float* __restrict__ Wa,
                             const float* __restrict__ Wo, const float* __restrict__ Wf,
                             unsigned short* __restrict__ dst)
{
    const int f = (blockIdx.x * 256 + threadIdx.x) * 4;
    const float* src; int off;
    if (f < 16384)      { src = We;            off = f; }
    else if (f < 32768) { src = Wa + 512 * 64; off = f - 16384; }
    else if (f < 98304) { src = Wo;            off = f - 32768; }
    else                { src = Wf;            off = f - 98304; }
    const float4 v = *(const float4*)&src[off];
    ushort4 o; o.x = f2bf(v.x); o.y = f2bf(v.y); o.z = f2bf(v.z); o.w = f2bf(v.w);
    *(ushort4*)&dst[f] = o;
}

// GEMM: Yout[p][m] = mask[p] * (sum_k W[m][k] * in[p][k] + bias[m]), bf16 MFMA.
// in[p][k]: MODE 0: x (fp32, channel-major global) raw
//           MODE 1: mask*relu(a*yprev+b), yprev bf16 [P][K]
//           MODE 2: MODE1 + x (residual) -> x1
// BN sum/sumsq fused into epilogue via bucketed atomics.
template<int BM, int MT, int K, int MODE>
__global__ __launch_bounds__(256, 2) void gemm_kernel(
    const unsigned short* __restrict__ Wb, const float* __restrict__ bias,
    const unsigned short* __restrict__ Yprev, const float* __restrict__ X0,
    const float* __restrict__ mask,
    const float* __restrict__ actA, const float* __restrict__ actB,
    unsigned short* __restrict__ Yout, float* __restrict__ partial)
{
    constexpr int LD = 40;                 // padded row stride (bf16 units) -> 80B, 2-way banks max
    constexpr int FM = 4;
    constexpr int FP = (BM == 128) ? 4 : 2;
    __shared__ unsigned short As[BM * LD];
    __shared__ unsigned short Bs[128 * LD];
    __shared__ float Ms[128];

    const int tid  = threadIdx.x;
    const int lane = tid & 63, w = tid >> 6, quad = lane >> 4, lt = lane & 15;
    const int mW = (BM == 128) ? (w >> 1) * 64 : 0;
    const int pW = (BM == 128) ? (w & 1) * 64 : w * 32;
    const int pBase = blockIdx.y * 128;
    const int m0g = blockIdx.x * BM;
    const int b  = pBase / kNV;
    const int q0 = pBase - b * kNV;

    if (tid < 128) Ms[tid] = mask[pBase + tid];
    __syncthreads();

    floatx4 acc[FM][FP];
    #pragma unroll
    for (int fm = 0; fm < FM; ++fm)
        #pragma unroll
        for (int fp = 0; fp < FP; ++fp) acc[fm][fp] = (floatx4)0.f;

    constexpr int AI = BM / 64;  // A-staging ushort8 loads per thread
    for (int k0 = 0; k0 < K; k0 += 32) {
        // ---- prefetch to registers ----
        ushort8 av[AI];
        #pragma unroll
        for (int i = 0; i < AI; ++i) {
            const int idx = tid + i * 256;
            const int m = idx >> 2, kq = (idx & 3) * 8;
            av[i] = *(const ushort8*)&Wb[(size_t)(m0g + m) * K + k0 + kq];
        }
        float bv[2][8];
        int bp[2], bkq[2];
        #pragma unroll
        for (int i = 0; i < 2; ++i) {
            const int idx = tid + i * 256;
            const int p = idx >> 2, kq = (idx & 3) * 8;
            bp[i] = p; bkq[i] = kq;
            if constexpr (MODE == 0) {
                #pragma unroll
                for (int j = 0; j < 8; ++j)
                    bv[i][j] = X0[(size_t)(b * kC + k0 + kq + j) * kNV + q0 + p];
            } else {
                const ushort8 y8 = *(const ushort8*)&Yprev[(size_t)(pBase + p) * K + k0 + kq];
                const float mp = Ms[p];
                #pragma unroll
                for (int j = 0; j < 8; ++j) {
                    float v = bf2f(y8[j]);
                    v = mp * fmaxf(fmaf(actA[k0 + kq + j], v, actB[k0 + kq + j]), 0.f);
                    if constexpr (MODE == 2)
                        v += X0[(size_t)(b * kC + k0 + kq + j) * kNV + q0 + p];
                    bv[i][j] = v;
                }
            }
        }
        __syncthreads();
        #pragma unroll
        for (int i = 0; i < AI; ++i) {
            const int idx = tid + i * 256;
            *(ushort8*)&As[(idx >> 2) * LD + (idx & 3) * 8] = av[i];
        }
        #pragma unroll
        for (int i = 0; i < 2; ++i) {
            ushort8 o;
            #pragma unroll
            for (int j = 0; j < 8; ++j) o[j] = f2bf(bv[i][j]);
            *(ushort8*)&Bs[bp[i] * LD + bkq[i]] = o;
        }
        __syncthreads();
        // ---- MFMA ----
        bf16x8 aF[FM], bF[FP];
        #pragma unroll
        for (int fm = 0; fm < FM; ++fm)
            aF[fm] = *(const bf16x8*)&As[(mW + fm * 16 + lt) * LD + quad * 8];
        #pragma unroll
        for (int fp = 0; fp < FP; ++fp)
            bF[fp] = *(const bf16x8*)&Bs[(pW + fp * 16 + lt) * LD + quad * 8];
        #pragma unroll
        for (int fm = 0; fm < FM; ++fm)
            #pragma unroll
            for (int fp = 0; fp < FP; ++fp)
                acc[fm][fp] = __builtin_amdgcn_mfma_f32_16x16x32_bf16(aF[fm], bF[fp], acc[fm][fp], 0, 0, 0);
    }

    // ---- epilogue: bias + mask, store bf16, fused stats ----
    float mpv[FP];
    #pragma unroll
    for (int fp = 0; fp < FP; ++fp) mpv[fp] = Ms[pW + fp * 16 + lt];
    float sumv[FM][4], sqv[FM][4];
    #pragma unroll
    for (int fm = 0; fm < FM; ++fm)
        #pragma unroll
        for (int i = 0; i < 4; ++i) { sumv[fm][i] = 0.f; sqv[fm][i] = 0.f; }

    #pragma unroll
    for (int fm = 0; fm < FM; ++fm) {
        float bia[4];
        #pragma unroll
        for (int i = 0; i < 4; ++i) bia[i] = bias[m0g + mW + fm * 16 + quad * 4 + i];
        #pragma unroll
        for (int fp = 0; fp < FP; ++fp) {
            const int pG = pBase + pW + fp * 16 + lt;
            float vv[4];
            #pragma unroll
            for (int i = 0; i < 4; ++i) {
                const float v = (acc[fm][fp][i] + bia[i]) * mpv[fp];
                vv[i] = v; sumv[fm][i] += v; sqv[fm][i] += v * v;
            }
            ushort4 o; o.x = f2bf(vv[0]); o.y = f2bf(vv[1]); o.z = f2bf(vv[2]); o.w = f2bf(vv[3]);
            *(ushort4*)&Yout[(size_t)pG * MT + m0g + mW + fm * 16 + quad * 4] = o;
        }
    }
    #pragma unroll
    for (int fm = 0; fm < FM; ++fm)
        #pragma unroll
        for (int i = 0; i < 4; ++i) {
            #pragma unroll
            for (int off = 1; off < 16; off <<= 1) {
                sumv[fm][i] += __shfl_xor(sumv[fm][i], off);
                sqv[fm][i]  += __shfl_xor(sqv[fm][i], off);
            }
        }
    if (lt == 0) {
        float* part = partial + (size_t)(blockIdx.y & 7) * 512;
        #pragma unroll
        for (int fm = 0; fm < FM; ++fm)
            #pragma unroll
            for (int i = 0; i < 4; ++i) {
                const int cG = m0g + mW + fm * 16 + quad * 4 + i;
                atomicAdd(&part[cG], sumv[fm][i]);
                atomicAdd(&part[256 + cG], sqv[fm][i]);
            }
    }
}

// fold BN into per-channel affine
__global__ void finalize_kernel(const float* __restrict__ part,
                                const float* __restrict__ g, const float* __restrict__ bt,
                                float* __restrict__ ab, int M)
{
    const int m = blockIdx.x * 64 + threadIdx.x;
    if (m >= M) return;
    float s = 0.f, s2 = 0.f;
    #pragma unroll
    for (int k = 0; k < 8; ++k) { s += part[k * 512 + m]; s2 += part[k * 512 + 256 + m]; }
    const float mu  = s * (1.f / kP);
    const float var = s2 * (1.f / kP) - mu * mu;
    const float A = rsqrtf(var + kEps) * g[m];
    ab[m] = A;
    ab[256 + m] = fmaf(-mu, A, bt[m]);
}

// out[c][q] = x + act3(y3) + act4(y4); y3/y4 are [P][256] bf16 -> transpose via LDS
__global__ __launch_bounds__(256) void final_kernel(
    const float* __restrict__ x, const unsigned short* __restrict__ y3,
    const unsigned short* __restrict__ y4,
    const float* __restrict__ p3, const float* __restrict__ p4,
    const float* __restrict__ mask, float* __restrict__ out)
{
    constexpr int TL = 258;                 // padded c-stride (ushort) -> 2-way banks max
    __shared__ unsigned short T3[32 * TL];
    __shared__ unsigned short T4[32 * TL];
    const int p0 = blockIdx.x * 32;
    const int b  = p0 / kNV;
    const int q0 = p0 - b * kNV;

    #pragma unroll
    for (int i = 0; i < 4; ++i) {
        const int idx = threadIdx.x + i * 256;
        const int p = idx >> 5, c0 = (idx & 31) * 8;
        *(ushort8*)&T3[p * TL + c0] = *(const ushort8*)&y3[(size_t)(p0 + p) * 256 + c0];
        *(ushort8*)&T4[p * TL + c0] = *(const ushort8*)&y4[(size_t)(p0 + p) * 256 + c0];
    }
    __syncthreads();

    const int qv = (threadIdx.x & 15) * 2;
    const int cb = threadIdx.x >> 4;
    const float m0v = mask[p0 + qv], m1v = mask[p0 + qv + 1];
    #pragma unroll
    for (int j = 0; j < 16; ++j) {
        const int c = cb + j * 16;
        const float a3 = p3[c], b3 = p3[256 + c], a4 = p4[c], b4 = p4[256 + c];
        const size_t ro = (size_t)(b * kC + c) * kNV + q0 + qv;
        const float2 xv = *(const float2*)&x[ro];
        const float v30 = bf2f(T3[qv * TL + c]),       v31 = bf2f(T3[(qv + 1) * TL + c]);
        const float v40 = bf2f(T4[qv * TL + c]),       v41 = bf2f(T4[(qv + 1) * TL + c]);
        float2 o;
        o.x = xv.x + m0v * (fmaxf(fmaf(a3, v30, b3), 0.f) + fmaxf(fmaf(a4, v40, b4), 0.f));
        o.y = xv.y + m1v * (fmaxf(fmaf(a3, v31, b3), 0.f) + fmaxf(fmaf(a4, v41, b4), 0.f));
        *(float2*)&out[ro] = o;
    }
}

extern "C" void kernel_launch(void* const* d_in, const int* in_sizes, int n_in,
                              void* d_out, int out_size, void* d_ws, size_t ws_size,
                              hipStream_t stream)
{
    const float* x    = (const float*)d_in[0];
    const float* mask = (const float*)d_in[1];
    const float* We   = (const float*)d_in[2];
    const float* be   = (const float*)d_in[3];
    const float* ge   = (const float*)d_in[4];
    const float* bne  = (const float*)d_in[5];
    const float* Wa   = (const float*)d_in[6];
    const float* ba   = (const float*)d_in[7];
    const float* ga   = (const float*)d_in[8];
    const float* bna  = (const float*)d_in[9];
    const float* Wo   = (const float*)d_in[10];
    const float* bo   = (const float*)d_in[11];
    const float* go   = (const float*)d_in[12];
    const float* bno  = (const float*)d_in[13];
    const float* Wf   = (const float*)d_in[14];
    const float* bf   = (const float*)d_in[15];
    const float* gf   = (const float*)d_in[16];
    const float* bnf  = (const float*)d_in[17];
    float* out = (float*)d_out;
    float* ws  = (float*)d_ws;

    float* params = ws + OFF_PARAMS;
    float* part   = ws + OFF_PART;
    unsigned short* Wb = (unsigned short*)(ws + OFF_WB);
    unsigned short* y1 = (unsigned short*)(ws + OFF_Y1);
    unsigned short* y2 = (unsigned short*)(ws + OFF_Y2);   // later reused as y4
    unsigned short* y3 = (unsigned short*)(ws + OFF_Y3);

    hipMemsetAsync(part, 0, 16384 * sizeof(float), stream);
    convw_kernel<<<160, 256, 0, stream>>>(We, Wa, Wo, Wf, Wb);

    const dim3 blk(256);
    const int PT = kP / 128;   // 768

    // stage 1: y1 = mask*(We @ x + be)  [P][64]
    gemm_kernel<64, 64, 256, 0><<<dim3(1, PT), blk, 0, stream>>>(
        Wb, be, nullptr, x, mask, nullptr, nullptr, y1, part);
    finalize_kernel<<<1, 64, 0, stream>>>(part, ge, bne, params, 64);

    // stage 2: y2 = mask*(Wa_v @ act1(y1) + ba_v)  [P][256]
    gemm_kernel<128, 256, 64, 1><<<dim3(2, PT), blk, 0, stream>>>(
        Wb + 16384, ba + 512, y1, nullptr, mask, params, params + 256, y2, part + 4096);
    finalize_kernel<<<4, 64, 0, stream>>>(part + 4096, ga + 512, bna + 512, params + 512, 256);

    // stage 3: y3 = mask*(Wo @ act2(y2) + bo)
    gemm_kernel<128, 256, 256, 1><<<dim3(2, PT), blk, 0, stream>>>(
        Wb + 32768, bo, y2, nullptr, mask, params + 512, params + 768, y3, part + 8192);
    finalize_kernel<<<4, 64, 0, stream>>>(part + 8192, go, bno, params + 1024, 256);

    // stage 4: y4 = mask*(Wf @ (x + act3(y3)) + bf)  (into y2's buffer)
    gemm_kernel<128, 256, 256, 2><<<dim3(2, PT), blk, 0, stream>>>(
        Wb + 98304, bf, y3, x, mask, params + 1024, params + 1280, y2, part + 12288);
    finalize_kernel<<<4, 64, 0, stream>>>(part + 12288, gf, bnf, params + 1536, 256);

    // final: out = x + act3(y3) + act4(y4)
    final_kernel<<<kP / 32, blk, 0, stream>>>(
        x, y3, y2, params + 1024, params + 1536, mask, out);
}